// Round 1
// baseline (1072.022 us; speedup 1.0000x reference)
//
#include <hip/hip_runtime.h>
#include <hip/hip_fp16.h>

// LSTM: B=256, T=512, IN=64, H=128, 2 layers + FC(128->1).
// Strategy: 1 workgroup per batch element (256 WGs, 512 threads = gate rows).
// All 4 weight matrices live in VGPRs as packed fp16 (224 VGPRs/thread);
// h-state in LDS as fp16, c-state + accumulators fp32, v_dot2_f32_f16 MACs.
// No workspace, no inter-WG communication.

#define BB 256
#define TT 512
#define IINN 64
#define HHH 128
#define GGG 512  // 4*H

typedef _Float16 f16x2 __attribute__((ext_vector_type(2)));

__device__ __forceinline__ f16x2 cvt2(float a, float b) {
    f16x2 r; r.x = (_Float16)a; r.y = (_Float16)b; return r;
}

__device__ __forceinline__ float fdot2_(f16x2 a, f16x2 b, float c) {
#if __has_builtin(__builtin_amdgcn_fdot2)
    return __builtin_amdgcn_fdot2(a, b, c, false);
#else
    return c + (float)a.x * (float)b.x + (float)a.y * (float)b.y;
#endif
}

__device__ __forceinline__ float sigmoid_f(float x) {
    // 1/(1+e^-x); rcp approx err ~1e-7, fine vs 9e-4 budget
    float e = __expf(-x);
    return __builtin_amdgcn_rcpf(1.0f + e);
}

__device__ __forceinline__ float tanh_f(float x) {
    // 1 - 2/(e^{2x}+1); inf-safe at both ends
    float e = __expf(2.0f * x);
    return 1.0f - 2.0f * __builtin_amdgcn_rcpf(e + 1.0f);
}

__global__ __launch_bounds__(512, 2) void lstm_fused(
    const float* __restrict__ x,
    const float* __restrict__ w_ih0, const float* __restrict__ w_hh0,
    const float* __restrict__ b_ih0, const float* __restrict__ b_hh0,
    const float* __restrict__ w_ih1, const float* __restrict__ w_hh1,
    const float* __restrict__ b_ih1, const float* __restrict__ b_hh1,
    const float* __restrict__ fc_w, const float* __restrict__ fc_b,
    float* __restrict__ out)
{
    const int g = threadIdx.x;   // gate row 0..511
    const int b = blockIdx.x;    // batch element

    __shared__ f16x2 xsh[2][IINN / 2];   // double-buffered x_t (fp16)
    __shared__ f16x2 h0sh[HHH / 2];      // layer0 h (fp16)
    __shared__ f16x2 h1sh[HHH / 2];      // layer1 h (fp16)
    __shared__ float gacts[GGG];         // activated gates (reused L0/L1)
    __shared__ float h1f[HHH];           // final-step fp32 h1 for FC

    // ---- load weight row g into registers as packed fp16 ----
    f16x2 wih0[IINN / 2], whh0[HHH / 2], wih1[HHH / 2], whh1[HHH / 2];
    {
        const float4* p = (const float4*)(w_ih0 + g * IINN);
        #pragma unroll
        for (int k = 0; k < IINN / 4; ++k) {
            float4 v = p[k];
            wih0[2 * k]     = cvt2(v.x, v.y);
            wih0[2 * k + 1] = cvt2(v.z, v.w);
        }
    }
    {
        const float4* p = (const float4*)(w_hh0 + g * HHH);
        #pragma unroll
        for (int k = 0; k < HHH / 4; ++k) {
            float4 v = p[k];
            whh0[2 * k]     = cvt2(v.x, v.y);
            whh0[2 * k + 1] = cvt2(v.z, v.w);
        }
    }
    {
        const float4* p = (const float4*)(w_ih1 + g * HHH);
        #pragma unroll
        for (int k = 0; k < HHH / 4; ++k) {
            float4 v = p[k];
            wih1[2 * k]     = cvt2(v.x, v.y);
            wih1[2 * k + 1] = cvt2(v.z, v.w);
        }
    }
    {
        const float4* p = (const float4*)(w_hh1 + g * HHH);
        #pragma unroll
        for (int k = 0; k < HHH / 4; ++k) {
            float4 v = p[k];
            whh1[2 * k]     = cvt2(v.x, v.y);
            whh1[2 * k + 1] = cvt2(v.z, v.w);
        }
    }
    const float bias0 = b_ih0[g] + b_hh0[g];
    const float bias1 = b_ih1[g] + b_hh1[g];

    // init state
    if (g < HHH / 2)       h0sh[g] = cvt2(0.f, 0.f);
    else if (g < HHH)      h1sh[g - HHH / 2] = cvt2(0.f, 0.f);
    if (g < 16) {
        float4 v = ((const float4*)x)[(b * TT + 0) * (IINN / 4) + g];
        xsh[0][2 * g]     = cvt2(v.x, v.y);
        xsh[0][2 * g + 1] = cvt2(v.z, v.w);
    }
    float c0 = 0.f, c1 = 0.f;
    __syncthreads();

    for (int t = 0; t < TT; ++t) {
        // prefetch x(t+1) into the other buffer (consumed after >=4 barriers)
        if (g < 16 && t + 1 < TT) {
            float4 v = ((const float4*)x)[(b * TT + t + 1) * (IINN / 4) + g];
            xsh[(t + 1) & 1][2 * g]     = cvt2(v.x, v.y);
            xsh[(t + 1) & 1][2 * g + 1] = cvt2(v.z, v.w);
        }

        // ---- P1: layer0 gate preact = bias0 + x.Wih0 + h0.Whh0 ----
        float a0 = bias0, a1 = 0.f, a2 = 0.f, a3 = 0.f;
        {
            const f16x2* xb = xsh[t & 1];
            #pragma unroll
            for (int k = 0; k < IINN / 2; k += 4) {
                a0 = fdot2_(xb[k + 0], wih0[k + 0], a0);
                a1 = fdot2_(xb[k + 1], wih0[k + 1], a1);
                a2 = fdot2_(xb[k + 2], wih0[k + 2], a2);
                a3 = fdot2_(xb[k + 3], wih0[k + 3], a3);
            }
            #pragma unroll
            for (int k = 0; k < HHH / 2; k += 4) {
                a0 = fdot2_(h0sh[k + 0], whh0[k + 0], a0);
                a1 = fdot2_(h0sh[k + 1], whh0[k + 1], a1);
                a2 = fdot2_(h0sh[k + 2], whh0[k + 2], a2);
                a3 = fdot2_(h0sh[k + 3], whh0[k + 3], a3);
            }
        }
        {
            float pre = (a0 + a1) + (a2 + a3);
            gacts[g] = (g >= 256 && g < 384) ? tanh_f(pre) : sigmoid_f(pre);
        }
        __syncthreads();  // B1

        // ---- P2: layer0 c/h update (threads 0..127) ----
        if (g < HHH) {
            float gi = gacts[g];
            float gf = gacts[g + HHH];
            float gg = gacts[g + 2 * HHH];
            float go = gacts[g + 3 * HHH];
            c0 = gf * c0 + gi * gg;
            float h = go * tanh_f(c0);
            ((_Float16*)h0sh)[g] = (_Float16)h;
        }
        __syncthreads();  // B2

        // ---- P3: layer1 gate preact = bias1 + h0_new.Wih1 + h1_old.Whh1 ----
        a0 = bias1; a1 = 0.f; a2 = 0.f; a3 = 0.f;
        {
            #pragma unroll
            for (int k = 0; k < HHH / 2; k += 4) {
                a0 = fdot2_(h0sh[k + 0], wih1[k + 0], a0);
                a1 = fdot2_(h0sh[k + 1], wih1[k + 1], a1);
                a2 = fdot2_(h0sh[k + 2], wih1[k + 2], a2);
                a3 = fdot2_(h0sh[k + 3], wih1[k + 3], a3);
            }
            #pragma unroll
            for (int k = 0; k < HHH / 2; k += 4) {
                a0 = fdot2_(h1sh[k + 0], whh1[k + 0], a0);
                a1 = fdot2_(h1sh[k + 1], whh1[k + 1], a1);
                a2 = fdot2_(h1sh[k + 2], whh1[k + 2], a2);
                a3 = fdot2_(h1sh[k + 3], whh1[k + 3], a3);
            }
        }
        {
            float pre = (a0 + a1) + (a2 + a3);
            gacts[g] = (g >= 256 && g < 384) ? tanh_f(pre) : sigmoid_f(pre);
        }
        __syncthreads();  // B3

        // ---- P4: layer1 c/h update ----
        if (g < HHH) {
            float gi = gacts[g];
            float gf = gacts[g + HHH];
            float gg = gacts[g + 2 * HHH];
            float go = gacts[g + 3 * HHH];
            c1 = gf * c1 + gi * gg;
            float h = go * tanh_f(c1);
            ((_Float16*)h1sh)[g] = (_Float16)h;
            if (t == TT - 1) h1f[g] = h;
        }
        __syncthreads();  // B4
    }

    // ---- FC epilogue: out[b] = sum_j fc_w[j]*h1f[j] + fc_b ----
    if (g < 64) {
        float p = h1f[g] * fc_w[g] + h1f[g + 64] * fc_w[g + 64];
        #pragma unroll
        for (int off = 32; off > 0; off >>= 1) p += __shfl_down(p, off, 64);
        if (g == 0) out[b] = p + fc_b[0];
    }
}

extern "C" void kernel_launch(void* const* d_in, const int* in_sizes, int n_in,
                              void* d_out, int out_size, void* d_ws, size_t ws_size,
                              hipStream_t stream) {
    const float* x     = (const float*)d_in[0];
    const float* w_ih0 = (const float*)d_in[1];
    const float* w_hh0 = (const float*)d_in[2];
    const float* b_ih0 = (const float*)d_in[3];
    const float* b_hh0 = (const float*)d_in[4];
    const float* w_ih1 = (const float*)d_in[5];
    const float* w_hh1 = (const float*)d_in[6];
    const float* b_ih1 = (const float*)d_in[7];
    const float* b_hh1 = (const float*)d_in[8];
    const float* fc_w  = (const float*)d_in[9];
    const float* fc_b  = (const float*)d_in[10];
    float* out = (float*)d_out;

    lstm_fused<<<dim3(BB), dim3(GGG), 0, stream>>>(
        x, w_ih0, w_hh0, b_ih0, b_hh0, w_ih1, w_hh1, b_ih1, b_hh1,
        fc_w, fc_b, out);
}